// Round 11
// baseline (166.919 us; speedup 1.0000x reference)
//
#include <hip/hip_runtime.h>
#include <stdint.h>

#define Nn 4
#define Cc 64
#define LL 4096   // H*W
#define KK 256    // feature dim: 64 channels * 4 causal taps
#define TRI2 528  // 32*33/2 triangular 128x128 tile pairs per batch

typedef _Float16 half8 __attribute__((ext_vector_type(8)));
typedef float f32x16 __attribute__((ext_vector_type(16)));
typedef float f4a __attribute__((ext_vector_type(4), aligned(4)));

__device__ __forceinline__ unsigned f2ord(float f) {
    unsigned u = __float_as_uint(f);
    return u ^ ((u & 0x80000000u) ? 0xFFFFFFFFu : 0x80000000u);
}
__device__ __forceinline__ float ord2f(unsigned o) {
    unsigned u = (o & 0x80000000u) ? (o ^ 0x80000000u) : ~o;
    return __uint_as_float(u);
}
__device__ __forceinline__ unsigned short h2u(_Float16 h) {
    union { _Float16 f; unsigned short u; } x; x.f = h; return x.u;
}

// Kernel 1: normalized masked context vectors, split fp16 hi/lo, pre-scaled
//   Vh' = 2048*fp16(v), Vl = fp16((v - fp16(v)) * 2048),
// written in FRAGMENT-MAJOR layout (the 32x32x16 MFMA A/B register image):
// element (l,k) -> [ ((l>>5)*16 + (k>>4))*64 + (l&31) + 32*((k>>3)&1) ]*8 + (k&7).
// XCD-pinned; zeroes its slice of `best`.
__global__ __launch_bounds__(256) void build_v(const float* __restrict__ yhat,
                                               unsigned short* __restrict__ VhT,
                                               unsigned short* __restrict__ VlT,
                                               unsigned long long* __restrict__ best) {
    int blk = blockIdx.x;                       // 0..1023
    int xcd = blk & 7;
    int n = xcd >> 1;
    int i64 = (blk >> 3) + (xcd & 1) * 128;     // 0..255; block covers l = i64*16 ..+16
    int tid = threadIdx.x;
    if (tid < 16) best[(size_t)n * LL + i64 * 16 + tid] = 0ull;

    int cg = tid & 15;           // k16 chunk owner (channels cg*4 .. cg*4+3)
    int l = i64 * 16 + (tid >> 4);
    int y = l >> 6, x = l & 63;
    const float* src = yhat + (size_t)n * (Cc * LL);

    float vals[16];
    float sumsq = 0.f;
#pragma unroll
    for (int ci = 0; ci < 4; ++ci) {
        const float* p = src + (cg * 4 + ci) * LL;
        float t0 = (y > 0 && x > 0)  ? p[l - 65] : 0.f;
        float t1 = (y > 0)           ? p[l - 64] : 0.f;
        float t2 = (y > 0 && x < 63) ? p[l - 63] : 0.f;
        float t3 = (x > 0)           ? p[l - 1]  : 0.f;
        vals[ci * 4 + 0] = t0; vals[ci * 4 + 1] = t1;
        vals[ci * 4 + 2] = t2; vals[ci * 4 + 3] = t3;
        sumsq += t0 * t0 + t1 * t1 + t2 * t2 + t3 * t3;
    }
    sumsq += __shfl_xor(sumsq, 1, 64);
    sumsq += __shfl_xor(sumsq, 2, 64);
    sumsq += __shfl_xor(sumsq, 4, 64);
    sumsq += __shfl_xor(sumsq, 8, 64);
    float inv = 1.f / fmaxf(sqrtf(sumsq), 1e-12f);

    __align__(16) unsigned short hs[16];
    __align__(16) unsigned short ls[16];
#pragma unroll
    for (int kl = 0; kl < 16; ++kl) {
        float v = vals[kl] * inv;
        _Float16 h = (fabsf(v) < 6.1035e-5f) ? (_Float16)0 : (_Float16)v;
        _Float16 lo = (_Float16)((v - (float)h) * 2048.0f);
        hs[kl] = h2u(h * (_Float16)2048.0f);   // exact pow2 scale
        ls[kl] = h2u(lo);
    }

    unsigned short* dhb = VhT + (size_t)n * (LL * KK);
    unsigned short* dlb = VlT + (size_t)n * (LL * KK);
    size_t gbase = ((size_t)((l >> 5) * 16 + cg)) * 64;
    size_t a0 = (gbase + (l & 31)) * 8;        // k-half 0
    size_t a1 = (gbase + 32 + (l & 31)) * 8;   // k-half 1
    *(uint4*)(dhb + a0) = *(const uint4*)&hs[0];
    *(uint4*)(dhb + a1) = *(const uint4*)&hs[8];
    *(uint4*)(dlb + a0) = *(const uint4*)&ls[0];
    *(uint4*)(dlb + a1) = *(const uint4*)&ls[8];
}

// Kernel 2: triangular 128x128-tiled similarity-max, NO LDS, NO BARRIERS,
// fragment-major direct-from-L2 loads with EXPLICIT register ping-pong
// prefetch: fragments for k16+1 are loaded while the 24 MFMAs of k16 run
// (768 SIMD-cyc of cover vs ~200-400 cyc L2 latency). MFMAs grouped by pass
// so 8 independent acc chains sit between dependent reuses.
// acc = Vh1'Vh2' + Vh1'Vl2 + Vl1Vh2' = 2^22 * v1.v2 ; val = acc * 2^-22.
// C/D: col=lane&31, row=(reg&3)+8*(reg>>2)+4*(lane>>5).
__global__ __launch_bounds__(128, 2) void simmax(const unsigned short* __restrict__ Vh,
                                                 const unsigned short* __restrict__ Vl,
                                                 unsigned long long* __restrict__ best) {
    int bx = blockIdx.x;              // 0..2111
    int xcd = bx & 7, idx = bx >> 3;  // XCD-pin: each XCD owns half of one batch
    int n = xcd >> 1;
    int t = (xcd & 1) * 264 + idx;    // 0..527
    int j = (int)((sqrtf(8.f * (float)t + 1.f) - 1.f) * 0.5f);
    while ((j + 1) * (j + 2) / 2 <= t) ++j;
    while (j * (j + 1) / 2 > t) --j;
    int i = t - j * (j + 1) / 2;
    int l0 = i * 128, m0 = j * 128;

    int tid = threadIdx.x;
    int w = tid >> 6, lane = tid & 63;
    int r5 = lane & 31, h5 = lane >> 5;
    int rw = w * 64;                  // wave rows (l): 0 or 64

    const unsigned short* VhB = Vh + (size_t)n * (LL * KK);
    const unsigned short* VlB = Vl + (size_t)n * (LL * KK);

    int gA = (l0 + rw) >> 5;          // + r (2 groups)
    int gB = m0 >> 5;                 // + c (4 groups)

    f32x16 acc[2][4];
#pragma unroll
    for (int r = 0; r < 2; ++r)
#pragma unroll
        for (int c = 0; c < 4; ++c) acc[r][c] = (f32x16)0.f;

    half8 ah[2][2], al[2][2], bh[2][4], bl[2][4];   // [buffer][frag]

#define LOADK(buf, k16) do {                                              \
    _Pragma("unroll")                                                     \
    for (int r = 0; r < 2; ++r) {                                         \
        size_t off = ((size_t)((gA + r) * 16 + (k16)) * 64 + lane) * 8;   \
        ah[buf][r] = *(const half8*)(VhB + off);                          \
        al[buf][r] = *(const half8*)(VlB + off);                          \
    }                                                                     \
    _Pragma("unroll")                                                     \
    for (int c = 0; c < 4; ++c) {                                         \
        size_t off = ((size_t)((gB + c) * 16 + (k16)) * 64 + lane) * 8;   \
        bh[buf][c] = *(const half8*)(VhB + off);                          \
        bl[buf][c] = *(const half8*)(VlB + off);                          \
    }                                                                     \
} while (0)

#define MFMAK(buf) do {                                                   \
    _Pragma("unroll")                                                     \
    for (int c = 0; c < 4; ++c)                                           \
    _Pragma("unroll")                                                     \
    for (int r = 0; r < 2; ++r)                                           \
        acc[r][c] = __builtin_amdgcn_mfma_f32_32x32x16_f16(al[buf][r], bh[buf][c], acc[r][c], 0, 0, 0); \
    _Pragma("unroll")                                                     \
    for (int c = 0; c < 4; ++c)                                           \
    _Pragma("unroll")                                                     \
    for (int r = 0; r < 2; ++r)                                           \
        acc[r][c] = __builtin_amdgcn_mfma_f32_32x32x16_f16(ah[buf][r], bl[buf][c], acc[r][c], 0, 0, 0); \
    _Pragma("unroll")                                                     \
    for (int c = 0; c < 4; ++c)                                           \
    _Pragma("unroll")                                                     \
    for (int r = 0; r < 2; ++r)                                           \
        acc[r][c] = __builtin_amdgcn_mfma_f32_32x32x16_f16(ah[buf][r], bh[buf][c], acc[r][c], 0, 0, 0); \
} while (0)

    LOADK(0, 0);
#pragma unroll
    for (int kk = 0; kk < 16; kk += 2) {
        LOADK(1, kk + 1);          // prefetch odd chunk
        MFMAK(0);                  // consume even chunk
        if (kk + 2 < 16) LOADK(0, kk + 2);   // prefetch next even chunk
        MFMAK(1);                  // consume odd chunk
    }
#undef LOADK
#undef MFMAK

    unsigned long long* bb = best + (size_t)n * LL;
    const float s = 1.f / 4194304.f;   // 2^-22
#pragma unroll
    for (int c = 0; c < 4; ++c) {
        int m = m0 + c * 32 + r5;
        unsigned long long key = 0ull;
#pragma unroll
        for (int r = 0; r < 2; ++r)
#pragma unroll
            for (int g = 0; g < 16; ++g) {
                int l = l0 + rw + r * 32 + (g & 3) + 8 * (g >> 2) + 4 * h5;
                if (l < m) {
                    float v = acc[r][c][g] * s;
                    unsigned long long k2 =
                        ((unsigned long long)f2ord(v) << 32) |
                        (unsigned long long)(0xFFFFFFFFu - (unsigned)l);
                    key = (k2 > key) ? k2 : key;
                }
            }
        unsigned long long o = __shfl_xor(key, 32, 64);
        key = (o > key) ? o : key;
        if (h5 == 0 && key != 0ull) atomicMax(bb + m, key);
    }
}

// Kernel 3: unpack best, write S, U, ref_unfold, arg (float values), m==0 overrides.
// 4096 blocks (16 channel-groups of 4) for TLP; XCD-pinned per batch.
__global__ __launch_bounds__(256) void writeout(const float* __restrict__ yhat,
                                                const float* __restrict__ yprob,
                                                const unsigned long long* __restrict__ best,
                                                float* __restrict__ out) {
    int blk = blockIdx.x;                     // 0..4095
    int xcd = blk & 7;
    int n = xcd >> 1;
    int idx = (blk >> 3) + (xcd & 1) * 512;   // 0..1023
    int mb = idx >> 4;                        // 0..63
    int fc = idx & 15;                        // channel group of 4
    int tid = threadIdx.x;
    int mm = tid & 63;
    int fs = tid >> 6;                        // 0..3
    int c = fc * 4 + fs;
    int m = mb * 64 + mm;

    unsigned long long key = best[(size_t)n * LL + m];
    unsigned l = 0xFFFFFFFFu - (unsigned)(key & 0xFFFFFFFFull);
    float val = ord2f((unsigned)(key >> 32));
    bool zero = (m == 0);
    if (zero) l = 0;
    int ly = (int)(l >> 6), lx = (int)(l & 63);

    float* Sout = out;                       // [4,1,64,64]
    float* Uout = out + 16384;               // [4,1,64,64]
    float* Rout = out + 32768;               // [4,576,4096]
    float* Aout = out + 9469952;             // [4,4096] as float values

    if (fc == 0 && fs == 0) {
        float S = zero ? 1e-8f : fminf(fmaxf(val, 1e-8f), 1.0f);
        float U = zero ? 1e-8f : fminf(fmaxf(yprob[(size_t)n * LL + l], 1e-8f), 1.0f);
        Sout[(size_t)n * LL + m] = S;
        Uout[(size_t)n * LL + m] = U;
        Aout[(size_t)n * LL + m] = zero ? -1.0f : (float)l;
    }

    const float* src = yhat + (size_t)n * (Cc * LL);
    const float* plane = src + (size_t)c * LL;
    float* dst = Rout + (size_t)n * (576 * LL) + m;
    bool fast = (!zero) && (lx >= 1) && (lx <= 61);
#pragma unroll
    for (int r3 = 0; r3 < 3; ++r3) {
        int yy = ly + r3 - 1;
        bool rowok = (!zero) && (yy >= 0) && (yy < 64);
        float t0 = 0.f, t1 = 0.f, t2 = 0.f;
        if (rowok) {
            if (fast) {
                f4a v = *(const f4a*)(plane + yy * 64 + lx - 1);
                t0 = v.x; t1 = v.y; t2 = v.z;
            } else {
                if (lx > 0)  t0 = plane[yy * 64 + lx - 1];
                t1 = plane[yy * 64 + lx];
                if (lx < 63) t2 = plane[yy * 64 + lx + 1];
            }
        }
        size_t f = (size_t)(c * 9 + r3 * 3) * LL;
        __builtin_nontemporal_store(t0, dst + f);
        __builtin_nontemporal_store(t1, dst + f + LL);
        __builtin_nontemporal_store(t2, dst + f + 2 * (size_t)LL);
    }
}

extern "C" void kernel_launch(void* const* d_in, const int* in_sizes, int n_in,
                              void* d_out, int out_size, void* d_ws, size_t ws_size,
                              hipStream_t stream) {
    const float* yhat  = (const float*)d_in[0];
    const float* yprob = (const float*)d_in[1];
    float* out = (float*)d_out;

    unsigned short* VhT = (unsigned short*)d_ws;                       // 8 MiB (fragment-major)
    unsigned short* VlT = (unsigned short*)((char*)d_ws + 8388608);    // 8 MiB (fragment-major)
    unsigned long long* best =
        (unsigned long long*)((char*)d_ws + 16777216);                 // 128 KiB

    build_v<<<1024, 256, 0, stream>>>(yhat, VhT, VlT, best);
    simmax<<<Nn * TRI2, 128, 0, stream>>>(VhT, VlT, best);
    writeout<<<4096, 256, 0, stream>>>(yhat, yprob, best, out);
}